// Round 6
// baseline (476.100 us; speedup 1.0000x reference)
//
#include <hip/hip_runtime.h>
#include <hip/hip_bf16.h>
#include <stdint.h>

#define N_ATOMS 20000
#define NFEAT   2784
#define KP1     2816      // 44 * 64, K-pad for packed W1 (2784 real + 32 zero)
#define SS      500
#define NPAD    20224     // 158 * 128
#define MCOLS   1024      // P*H

typedef __attribute__((ext_vector_type(8))) short s16x8;
typedef __attribute__((ext_vector_type(4))) float f32x4;

static __device__ __forceinline__ unsigned short f2b(float f) {
    __hip_bfloat16 h = __float2bfloat16(f);
    return __builtin_bit_cast(unsigned short, h);
}
static __device__ __forceinline__ float b2f(unsigned short u) {
    unsigned int x = ((unsigned int)u) << 16;
    return __builtin_bit_cast(float, x);
}

#define GLOAD16(g, l) __builtin_amdgcn_global_load_lds( \
    (const __attribute__((address_space(1))) void*)(g), \
    (__attribute__((address_space(3))) void*)(l), 16, 0, 0)

// W fp32 [P][KD][256] -> Bt bf16 [1024][KP];  Bt[p*256+h][k] = W[p][k][h], 0 for k>=KD
__global__ void pack_w(const float* __restrict__ W, unsigned short* __restrict__ Bt,
                       int KD, int KP) {
    __shared__ unsigned short tile[32][256];
    int p = blockIdx.y;
    int f0 = blockIdx.x * 32;
    int t = threadIdx.x;
    #pragma unroll 4
    for (int i = 0; i < 32; ++i) {
        int f = f0 + i;
        float v = (f < KD) ? W[((size_t)p * KD + f) * 256 + t] : 0.f;
        tile[i][t] = f2b(v);
    }
    __syncthreads();
    unsigned short* drow = Bt + (size_t)(p * 256 + t) * KP + f0;
    #pragma unroll
    for (int i = 0; i < 32; i += 4) {
        ushort4 o;
        o.x = tile[i][t]; o.y = tile[i + 1][t]; o.z = tile[i + 2][t]; o.w = tile[i + 3][t];
        *(ushort4*)(drow + i) = o;
    }
}

// Fused small prep: blocks [0,32) pack W2, [32,64) pack W3, [64,143) make_pw,
// [143] zero out. [R4/R5-verified]
__global__ void prep_small(const float* __restrict__ W2, const float* __restrict__ W3,
                           unsigned short* __restrict__ B2t, unsigned short* __restrict__ B3t,
                           const float* __restrict__ Wc, const int* __restrict__ spec,
                           float* __restrict__ pw, float* __restrict__ out) {
    __shared__ unsigned short tile[32][256];
    int b = blockIdx.x;
    int t = threadIdx.x;
    if (b < 64) {
        const float* W = (b < 32) ? W2 : W3;
        unsigned short* Bt = (b < 32) ? B2t : B3t;
        int bb = b & 31;
        int p = bb >> 3;
        int f0 = (bb & 7) * 32;
        #pragma unroll 4
        for (int i = 0; i < 32; ++i) {
            int f = f0 + i;
            tile[i][t] = f2b(W[((size_t)p * 256 + f) * 256 + t]);
        }
        __syncthreads();
        unsigned short* drow = Bt + (size_t)(p * 256 + t) * 256 + f0;
        #pragma unroll
        for (int i = 0; i < 32; i += 4) {
            ushort4 o;
            o.x = tile[i][t]; o.y = tile[i + 1][t]; o.z = tile[i + 2][t]; o.w = tile[i + 3][t];
            *(ushort4*)(drow + i) = o;
        }
    } else if (b < 143) {
        int n = (b - 64) * 256 + t;
        if (n < N_ATOMS) {
            int s = spec[n];
            float4 v = *(const float4*)(Wc + s * 4);
            *(float4*)(pw + n * 4) = v;
        }
    } else {
        for (int i = t; i < SS; i += 256) out[i] = 0.f;
    }
}

// ---------------- Layer-1 FUSED (v2): fp32 features read directly ---------------
// R5's proven BK=64 / 64KB dbuf / 2-blocks-per-CU skeleton, with the A-side
// global_load_lds replaced by LEAD-2 register staging + in-kernel bf16 convert.
// Key fix vs R2 (lead-1, mid-step vmcnt(2), MfmaUtil 16): per step t the issue
// order is [A-loads tile t+4 (4x dwordx4)] then [B-gloads tile t+2 (2)], so the
// END-OF-STEP vmcnt(6) (= exactly those 6) already guarantees A(t+2) and B(t+1)
// landed -> NO mid-step wait; A latency covered by ~2 full steps.
// OOB: row/k address CLAMP only; B1t zero k-columns (2784..2815) annihilate
// clamped A garbage. 44 uniform steps; steps 42/43 stage never-consumed data
// (B reads stay within the +4KB slack after B1t).
__global__ __launch_bounds__(512, 4) void gemm1_fused(
    const float* __restrict__ F,
    const unsigned short* __restrict__ Bt,
    const float* __restrict__ pw,
    unsigned short* __restrict__ C)
{
    __shared__ __align__(16) unsigned short lds_a[2 * 8192];   // 32 KB
    __shared__ __align__(16) unsigned short lds_b[2 * 8192];   // 32 KB

    int bid = blockIdx.x;
    int swz = (bid & 7) * 158 + (bid >> 3);  // bijective XCD chunking (1264 = 8*158)
    int rowTile = swz >> 3;                  // 0..157
    int colTile = swz & 7;                   // 0..7
    int rowBase = rowTile * 128;
    int colBase = colTile * 128;
    int p = colTile >> 1;                    // pseudo-species of this 128-col slab

    int t0 = threadIdx.x;
    int wave = t0 >> 6;
    int lane = t0 & 63;
    int wm = wave >> 1;      // 0..3  (32-row slab)
    int wn = wave & 1;       // 0..1  (64-col slab)

    // ---- A staging geometry: thread covers rows rA, rA+64; logical chunk cl ----
    int rA = t0 >> 3;                 // 0..63
    int cl = t0 & 7;                  // logical 8-elem chunk within the 64-K row
    int cl8 = cl << 3;
    int pc = cl ^ (rA & 7);           // phys chunk (XOR swizzle) for ds_write
    int ar0 = rowBase + rA;      if (ar0 > N_ATOMS - 1) ar0 = N_ATOMS - 1;
    int ar1 = rowBase + rA + 64; if (ar1 > N_ATOMS - 1) ar1 = N_ATOMS - 1;
    const float* fa0 = F + (size_t)ar0 * NFEAT;
    const float* fa1 = F + (size_t)ar1 * NFEAT;
    unsigned short* wA0 = lds_a + rA * 64 + pc * 8;
    unsigned short* wA1 = lds_a + (rA + 64) * 64 + pc * 8;

    // ---- B staging: linear LDS dest, inverse-swizzled global k (as R5) ----
    const unsigned short* sb = Bt + (size_t)(colBase + rA) * KP1 + (pc << 3);

    // fragment read bases
    int ra0 = wm * 32 + (lane & 15);
    int rb0 = wn * 64 + (lane & 15);
    int xr = lane & 7;
    int c0 = lane >> 4;

    f32x4 acc[2][4];
    f32x4 z4 = {0.f, 0.f, 0.f, 0.f};
    #pragma unroll
    for (int i = 0; i < 2; ++i)
        #pragma unroll
        for (int j = 0; j < 4; ++j) acc[i][j] = z4;

#define AISSUE(KO, R0_, R1_, R2_, R3_) do { \
    int ko = (KO) + cl8; if (ko > NFEAT - 8) ko = NFEAT - 8; \
    R0_ = *(const float4*)(fa0 + ko); \
    R1_ = *(const float4*)(fa0 + ko + 4); \
    R2_ = *(const float4*)(fa1 + ko); \
    R3_ = *(const float4*)(fa1 + ko + 4); \
} while (0)

#define AWRITE(SB, C0, C1, C2, C3) do { \
    s16x8 w0, w1; \
    w0[0] = (short)f2b((C0).x); w0[1] = (short)f2b((C0).y); \
    w0[2] = (short)f2b((C0).z); w0[3] = (short)f2b((C0).w); \
    w0[4] = (short)f2b((C1).x); w0[5] = (short)f2b((C1).y); \
    w0[6] = (short)f2b((C1).z); w0[7] = (short)f2b((C1).w); \
    w1[0] = (short)f2b((C2).x); w1[1] = (short)f2b((C2).y); \
    w1[2] = (short)f2b((C2).z); w1[3] = (short)f2b((C2).w); \
    w1[4] = (short)f2b((C3).x); w1[5] = (short)f2b((C3).y); \
    w1[6] = (short)f2b((C3).z); w1[7] = (short)f2b((C3).w); \
    *(s16x8*)(wA0 + (SB) * 8192) = w0; \
    *(s16x8*)(wA1 + (SB) * 8192) = w1; \
} while (0)

#define BGLOAD(SB) do { \
    GLOAD16(sb, lds_b + (SB) * 8192 + t0 * 8); \
    GLOAD16(sb + (size_t)64 * KP1, lds_b + (SB) * 8192 + 4096 + t0 * 8); \
    sb += 64; \
} while (0)

    // ---------------- prologue ----------------
    float4 a00, a01, a02, a03;   // regset 0
    float4 a10, a11, a12, a13;   // regset 1
    AISSUE(0,   a00, a01, a02, a03);   // tile 0 -> S0
    __builtin_amdgcn_sched_barrier(0);
    AISSUE(64,  a10, a11, a12, a13);   // tile 1 -> S1
    __builtin_amdgcn_sched_barrier(0);
    BGLOAD(0);                          // B tile 0
    BGLOAD(1);                          // B tile 1
    asm volatile("s_waitcnt vmcnt(8)" ::: "memory");   // A(0) landed
    AWRITE(0, a00, a01, a02, a03);
    AISSUE(128, a00, a01, a02, a03);   // tile 2 -> S0
    __builtin_amdgcn_sched_barrier(0);
    asm volatile("s_waitcnt vmcnt(8)" ::: "memory");   // A(1) landed
    AWRITE(1, a10, a11, a12, a13);
    AISSUE(192, a10, a11, a12, a13);   // tile 3 -> S1
    __builtin_amdgcn_sched_barrier(0);
    asm volatile("s_waitcnt vmcnt(10) lgkmcnt(0)" ::: "memory");  // B(0) landed, A-writes drained
    __builtin_amdgcn_s_barrier();
    __builtin_amdgcn_sched_barrier(0);

    int ako = 256;   // k-base of next A-reg issue (tile 4)

// Step t on buffer CB=t&1 (tile t landed): frag-read, read-done barrier,
// AWRITE regset (tile t+2, guaranteed landed by end-of-(t-1) vmcnt(6)),
// reissue regset for tile t+4, B-gload tile t+2, MFMA, vmcnt(6), barrier.
#define FSTEP(CB, C0, C1, C2, C3) do { \
    s16x8 af[2][2], bv[2][4]; \
    _Pragma("unroll") \
    for (int kk = 0; kk < 2; ++kk) { \
        int ch = ((((kk << 2) | c0) ^ xr) << 3); \
        _Pragma("unroll") \
        for (int fm = 0; fm < 2; ++fm) \
            af[kk][fm] = *(const s16x8*)&lds_a[(CB) * 8192 + (ra0 + fm * 16) * 64 + ch]; \
        _Pragma("unroll") \
        for (int fn = 0; fn < 4; ++fn) \
            bv[kk][fn] = *(const s16x8*)&lds_b[(CB) * 8192 + (rb0 + fn * 16) * 64 + ch]; \
    } \
    asm volatile("s_waitcnt lgkmcnt(0)" ::: "memory"); \
    __builtin_amdgcn_sched_barrier(0); \
    __builtin_amdgcn_s_barrier();            /* all waves done reading CB */ \
    __builtin_amdgcn_sched_barrier(0); \
    AWRITE(CB, C0, C1, C2, C3);              /* tile t+2 -> lds_a[CB] */ \
    AISSUE(ako, C0, C1, C2, C3);             /* tile t+4 -> same regset */ \
    ako += 64; \
    __builtin_amdgcn_sched_barrier(0); \
    BGLOAD(CB);                              /* B tile t+2 -> lds_b[CB] */ \
    __builtin_amdgcn_s_setprio(1); \
    _Pragma("unroll") \
    for (int kk = 0; kk < 2; ++kk) \
        _Pragma("unroll") \
        for (int fm = 0; fm < 2; ++fm) \
            _Pragma("unroll") \
            for (int fn = 0; fn < 4; ++fn) \
                acc[fm][fn] = __builtin_amdgcn_mfma_f32_16x16x32_bf16( \
                    af[kk][fm], bv[kk][fn], acc[fm][fn], 0, 0, 0); \
    __builtin_amdgcn_s_setprio(0); \
    asm volatile("s_waitcnt vmcnt(6) lgkmcnt(0)" ::: "memory"); /* B(t+1)+A(t+3) in */ \
    __builtin_amdgcn_s_barrier(); \
    __builtin_amdgcn_sched_barrier(0); \
} while (0)

    // 44 uniform steps (tiles 0..43). Steps 42/43 stage tiles 44/45: A clamped,
    // B within slack — never consumed.
    for (int it = 0; it < 22; ++it) {
        FSTEP(0, a00, a01, a02, a03);
        FSTEP(1, a10, a11, a12, a13);
    }
#undef FSTEP
#undef BGLOAD
#undef AWRITE
#undef AISSUE

    // drain pending gload_lds before LDS goes away with the block
    asm volatile("s_waitcnt vmcnt(0) lgkmcnt(0)" ::: "memory");

    // epilogue: C/D map col=lane&15, row=(lane>>4)*4+j  [m89-verified]
    int rGrp = (lane >> 4) << 2;
    int cLane = lane & 15;
    #pragma unroll
    for (int fm = 0; fm < 2; ++fm) {
        int r0 = rowBase + wm * 32 + fm * 16 + rGrp;
        float pwv[4];
        #pragma unroll
        for (int j = 0; j < 4; ++j) pwv[j] = pw[(size_t)(r0 + j) * 4 + p];
        #pragma unroll
        for (int fn = 0; fn < 4; ++fn) {
            int c = colBase + wn * 64 + fn * 16 + cLane;
            f32x4 a = acc[fm][fn];
            #pragma unroll
            for (int j = 0; j < 4; ++j) {
                float x = a[j] * pwv[j];
                float s = x / (1.f + __expf(-x));
                C[(size_t)(r0 + j) * MCOLS + c] = f2b(s);
            }
        }
    }
}

// ---------------- Layers 2/3: 128x128 tile, 2x2 waves, BK=64 (block-diag) -------
// [R1/R5-proven tail]
template<int USE_PW>
__global__ __launch_bounds__(256, 2) void gemm_silu(
    const unsigned short* __restrict__ A, int lda,
    const unsigned short* __restrict__ Bt, int ldb,
    int K, int aOffPerP,
    const float* __restrict__ pw,
    unsigned short* __restrict__ C)
{
    __shared__ __align__(16) unsigned short lds_a[128 * 64];
    __shared__ __align__(16) unsigned short lds_b[128 * 64];

    int bid = blockIdx.x;
    int colTile = bid & 7;
    int rowTile = bid >> 3;
    int rowBase = rowTile * 128;
    int colBase = colTile * 128;
    int p = colBase >> 8;
    int aOff = p * aOffPerP;

    int t = threadIdx.x;
    int wave = t >> 6;
    int lane = t & 63;
    int wm = wave >> 1, wn = wave & 1;

    int trow = t >> 3;
    int kcol = (((t & 7) ^ (trow & 7)) << 3);
    const unsigned short* srcA = A + (size_t)(rowBase + trow) * lda + aOff + kcol;
    const unsigned short* srcB = Bt + (size_t)(colBase + trow) * ldb + kcol;

    f32x4 acc[4][4];
    f32x4 z4 = {0.f, 0.f, 0.f, 0.f};
    #pragma unroll
    for (int i = 0; i < 4; ++i)
        #pragma unroll
        for (int j = 0; j < 4; ++j) acc[i][j] = z4;

    int rb = wm * 64 + (lane & 15);
    int cb = wn * 64 + (lane & 15);
    int c0 = lane >> 4;
    int xr = lane & 7;

    int KT = K >> 6;
    for (int kt = 0; kt < KT; ++kt) {
        #pragma unroll
        for (int i = 0; i < 4; ++i) {
            GLOAD16(srcA + (size_t)i * 32 * lda, lds_a + i * 2048 + wave * 512);
            GLOAD16(srcB + (size_t)i * 32 * ldb, lds_b + i * 2048 + wave * 512);
        }
        srcA += 64; srcB += 64;
        __syncthreads();

        #pragma unroll
        for (int kk = 0; kk < 2; ++kk) {
            s16x8 af[4], bfr[4];
            int ch = (((kk << 2) | c0) ^ xr) << 3;
            #pragma unroll
            for (int fm = 0; fm < 4; ++fm)
                af[fm] = *(const s16x8*)&lds_a[(rb + fm * 16) * 64 + ch];
            #pragma unroll
            for (int fn = 0; fn < 4; ++fn)
                bfr[fn] = *(const s16x8*)&lds_b[(cb + fn * 16) * 64 + ch];
            #pragma unroll
            for (int fm = 0; fm < 4; ++fm)
                #pragma unroll
                for (int fn = 0; fn < 4; ++fn)
                    acc[fm][fn] = __builtin_amdgcn_mfma_f32_16x16x32_bf16(
                        af[fm], bfr[fn], acc[fm][fn], 0, 0, 0);
        }
        __syncthreads();
    }

    int rGrp = (lane >> 4) << 2;
    int cLane = lane & 15;
    #pragma unroll
    for (int fm = 0; fm < 4; ++fm) {
        int r0 = rowBase + wm * 64 + fm * 16 + rGrp;
        float pwv[4];
        if (USE_PW) {
            #pragma unroll
            for (int j = 0; j < 4; ++j) pwv[j] = pw[(size_t)(r0 + j) * 4 + p];
        }
        #pragma unroll
        for (int fn = 0; fn < 4; ++fn) {
            int c = colBase + wn * 64 + fn * 16 + cLane;
            f32x4 a = acc[fm][fn];
            #pragma unroll
            for (int j = 0; j < 4; ++j) {
                float x = a[j];
                if (USE_PW) x *= pwv[j];
                float s = x / (1.f + __expf(-x));
                C[(size_t)(r0 + j) * MCOLS + c] = f2b(s);
            }
        }
    }
}

// e[n] = sum_{p,h} h3[n, p*256+h] * W4flat[p*256+h] * 0.5; atomicAdd(out[sidx[n]], e/40)
__global__ void finalize(const unsigned short* __restrict__ h3,
                         const float* __restrict__ W4,
                         const int* __restrict__ sidx,
                         float* __restrict__ out) {
    int atom = blockIdx.x * 4 + (threadIdx.x >> 6);
    int lane = threadIdx.x & 63;
    if (atom >= N_ATOMS) return;
    const uint32_t* hu = (const uint32_t*)(h3 + (size_t)atom * MCOLS) + lane * 8;
    const float* w = W4 + lane * 16;
    float sum = 0.f;
    #pragma unroll
    for (int i = 0; i < 8; ++i) {
        uint32_t u = hu[i];
        sum += b2f((unsigned short)(u & 0xffff)) * w[2 * i];
        sum += b2f((unsigned short)(u >> 16)) * w[2 * i + 1];
    }
    #pragma unroll
    for (int off = 32; off > 0; off >>= 1) sum += __shfl_down(sum, off);
    if (lane == 0) atomicAdd(out + sidx[atom], sum * 0.0125f);  // (1/sqrt(4))/40
}

extern "C" void kernel_launch(void* const* d_in, const int* in_sizes, int n_in,
                              void* d_out, int out_size, void* d_ws, size_t ws_size,
                              hipStream_t stream) {
    const float* features = (const float*)d_in[0];
    const float* W_comb   = (const float*)d_in[1];
    const float* W1       = (const float*)d_in[2];
    const float* W2       = (const float*)d_in[3];
    const float* W3       = (const float*)d_in[4];
    const float* W4       = (const float*)d_in[5];
    const int*   species  = (const int*)d_in[6];
    const int*   sidx     = (const int*)d_in[7];
    float* out = (float*)d_out;

    char* ws = (char*)d_ws;
    size_t off = 0;
    auto carve = [&](size_t bytes) {
        char* r = ws + off;
        off += (bytes + 255) & ~(size_t)255;
        return r;
    };
    unsigned short* B1t  = (unsigned short*)carve((size_t)1024 * KP1 * 2 + 4096); // 5.8 MB + slack
    unsigned short* B2t  = (unsigned short*)carve((size_t)1024 * 256 * 2);
    unsigned short* B3t  = (unsigned short*)carve((size_t)1024 * 256 * 2);
    float*          pw   = (float*)carve((size_t)NPAD * 4 * 4);
    unsigned short* h1   = (unsigned short*)carve((size_t)NPAD * 1024 * 2);  // 41.4 MB
    unsigned short* h2   = (unsigned short*)carve((size_t)NPAD * 1024 * 2);  // 41.4 MB
    carve(4096);                                                             // slack

    pack_w<<<dim3(KP1 / 32, 4), 256, 0, stream>>>(W1, B1t, NFEAT, KP1);
    prep_small<<<144, 256, 0, stream>>>(W2, W3, B2t, B3t, W_comb, species, pw, out);

    // layer 1 (fused fp32->bf16 A-path): [NPAD x 2784] * [2784 x 1024] -> h1
    gemm1_fused<<<158 * 8, 512, 0, stream>>>(features, B1t, pw, h1);
    // layer 2: block-diagonal, A col offset p*256
    gemm_silu<0><<<158 * 8, 256, 0, stream>>>(h1, 1024, B2t, 256, 256, 256, nullptr, h2);
    // layer 3
    gemm_silu<0><<<158 * 8, 256, 0, stream>>>(h2, 1024, B3t, 256, 256, 256, nullptr, h1);
    // layer 4 + segment sum
    finalize<<<N_ATOMS / 4, 256, 0, stream>>>(h1, W4, sidx, out);
}

// Round 7
// 317.626 us; speedup vs baseline: 1.4989x; 1.4989x over previous
//
#include <hip/hip_runtime.h>
#include <hip/hip_bf16.h>
#include <stdint.h>

#define N_ATOMS 20000
#define NFEAT   2784
#define KP1     2816      // 44 * 64, K-pad for packed W1 (2784 real + 32 zero)
#define SS      500
#define NPAD    20224     // 158 * 128
#define MCOLS   1024      // P*H

typedef __attribute__((ext_vector_type(8))) short s16x8;
typedef __attribute__((ext_vector_type(4))) float f32x4;

static __device__ __forceinline__ unsigned short f2b(float f) {
    __hip_bfloat16 h = __float2bfloat16(f);
    return __builtin_bit_cast(unsigned short, h);
}
static __device__ __forceinline__ float b2f(unsigned short u) {
    unsigned int x = ((unsigned int)u) << 16;
    return __builtin_bit_cast(float, x);
}

#define GLOAD16(g, l) __builtin_amdgcn_global_load_lds( \
    (const __attribute__((address_space(1))) void*)(g), \
    (__attribute__((address_space(3))) void*)(l), 16, 0, 0)

// W fp32 [P][KD][256] -> Bt bf16 [1024][KP];  Bt[p*256+h][k] = W[p][k][h], 0 for k>=KD
__global__ void pack_w(const float* __restrict__ W, unsigned short* __restrict__ Bt,
                       int KD, int KP) {
    __shared__ unsigned short tile[32][256];
    int p = blockIdx.y;
    int f0 = blockIdx.x * 32;
    int t = threadIdx.x;
    #pragma unroll 4
    for (int i = 0; i < 32; ++i) {
        int f = f0 + i;
        float v = (f < KD) ? W[((size_t)p * KD + f) * 256 + t] : 0.f;
        tile[i][t] = f2b(v);
    }
    __syncthreads();
    unsigned short* drow = Bt + (size_t)(p * 256 + t) * KP + f0;
    #pragma unroll
    for (int i = 0; i < 32; i += 4) {
        ushort4 o;
        o.x = tile[i][t]; o.y = tile[i + 1][t]; o.z = tile[i + 2][t]; o.w = tile[i + 3][t];
        *(ushort4*)(drow + i) = o;
    }
}

// Fused small prep: blocks [0,32) pack W2, [32,64) pack W3, [64,143) make_pw,
// [143] zero out. [R4/R5-verified]
__global__ void prep_small(const float* __restrict__ W2, const float* __restrict__ W3,
                           unsigned short* __restrict__ B2t, unsigned short* __restrict__ B3t,
                           const float* __restrict__ Wc, const int* __restrict__ spec,
                           float* __restrict__ pw, float* __restrict__ out) {
    __shared__ unsigned short tile[32][256];
    int b = blockIdx.x;
    int t = threadIdx.x;
    if (b < 64) {
        const float* W = (b < 32) ? W2 : W3;
        unsigned short* Bt = (b < 32) ? B2t : B3t;
        int bb = b & 31;
        int p = bb >> 3;
        int f0 = (bb & 7) * 32;
        #pragma unroll 4
        for (int i = 0; i < 32; ++i) {
            int f = f0 + i;
            tile[i][t] = f2b(W[((size_t)p * 256 + f) * 256 + t]);
        }
        __syncthreads();
        unsigned short* drow = Bt + (size_t)(p * 256 + t) * 256 + f0;
        #pragma unroll
        for (int i = 0; i < 32; i += 4) {
            ushort4 o;
            o.x = tile[i][t]; o.y = tile[i + 1][t]; o.z = tile[i + 2][t]; o.w = tile[i + 3][t];
            *(ushort4*)(drow + i) = o;
        }
    } else if (b < 143) {
        int n = (b - 64) * 256 + t;
        if (n < N_ATOMS) {
            int s = spec[n];
            float4 v = *(const float4*)(Wc + s * 4);
            *(float4*)(pw + n * 4) = v;
        }
    } else {
        for (int i = t; i < SS; i += 256) out[i] = 0.f;
    }
}

// ---------------- Layer-1 FUSED (v3): fp32 features, A TRIPLE-BUFFER ------------
// R5's proven BK=64 / 2-blocks-per-CU / counted-vmcnt skeleton. A-side: ONE
// 16-reg fp32 set (fix for R6's spill: WRITE_SIZE 400MB = scratch write-back;
// two regsets pushed peak regs past the 128 cap of launch_bounds(512,4)).
// A triple-buffer (3x16KB) lets AWRITE(t+2) happen at step-t START (last readers
// of that buffer were step t-1, sealed by its barriers), so the regset lives
// issue(step t-1, early) -> write(step t start) ~0.9 step >> HBM latency.
// Queue discipline (A oldest): per step [AISSUE(t+3) x4] ... [BGLOAD(t+2) x2];
// entry vmcnt(2) drains exactly A(t+2); end vmcnt(6) drains B(t+1). LDS 80KB
// (A 48 + B 32) -> exactly 2 blocks/CU. OOB rows/k: address clamp only; B1t's
// zero k-columns (2784..2815) annihilate clamped A garbage.
__global__ __launch_bounds__(512, 4) void gemm1_fused(
    const float* __restrict__ F,
    const unsigned short* __restrict__ Bt,
    const float* __restrict__ pw,
    unsigned short* __restrict__ C)
{
    __shared__ __align__(16) unsigned short lds_a[3 * 8192];   // 48 KB
    __shared__ __align__(16) unsigned short lds_b[2 * 8192];   // 32 KB

    int bid = blockIdx.x;
    int swz = (bid & 7) * 158 + (bid >> 3);  // bijective XCD chunking (1264 = 8*158)
    int rowTile = swz >> 3;                  // 0..157
    int colTile = swz & 7;                   // 0..7
    int rowBase = rowTile * 128;
    int colBase = colTile * 128;
    int p = colTile >> 1;                    // pseudo-species of this 128-col slab

    int t0 = threadIdx.x;
    int wave = t0 >> 6;
    int lane = t0 & 63;
    int wm = wave >> 1;      // 0..3  (32-row slab)
    int wn = wave & 1;       // 0..1  (64-col slab)

    // ---- A staging geometry: thread covers rows rA, rA+64; logical chunk cl ----
    int rA = t0 >> 3;                 // 0..63
    int cl = t0 & 7;                  // logical 8-elem chunk within the 64-K row
    int cl8 = cl << 3;
    int pc = cl ^ (rA & 7);           // phys chunk (XOR swizzle) for ds_write
    int ar0 = rowBase + rA;      if (ar0 > N_ATOMS - 1) ar0 = N_ATOMS - 1;
    int ar1 = rowBase + rA + 64; if (ar1 > N_ATOMS - 1) ar1 = N_ATOMS - 1;
    const float* fa0 = F + (size_t)ar0 * NFEAT;
    const float* fa1 = F + (size_t)ar1 * NFEAT;
    unsigned short* wA0 = lds_a + rA * 64 + pc * 8;
    unsigned short* wA1 = lds_a + (rA + 64) * 64 + pc * 8;

    // ---- B staging: linear LDS dest, inverse-swizzled global k (as R5) ----
    const unsigned short* sb = Bt + (size_t)(colBase + rA) * KP1 + (pc << 3);

    // fragment read bases
    int ra0 = wm * 32 + (lane & 15);
    int rb0 = wn * 64 + (lane & 15);
    int xr = lane & 7;
    int c0 = lane >> 4;

    f32x4 acc[2][4];
    f32x4 z4 = {0.f, 0.f, 0.f, 0.f};
    #pragma unroll
    for (int i = 0; i < 2; ++i)
        #pragma unroll
        for (int j = 0; j < 4; ++j) acc[i][j] = z4;

    float4 av0, av1, av2, av3;   // the single fp32 regset (16 VGPR)
    int ako = 0;                 // k-base of next AISSUE

#define AISSUE() do { \
    int ko = ako + cl8; if (ko > NFEAT - 8) ko = NFEAT - 8; \
    av0 = *(const float4*)(fa0 + ko); \
    av1 = *(const float4*)(fa0 + ko + 4); \
    av2 = *(const float4*)(fa1 + ko); \
    av3 = *(const float4*)(fa1 + ko + 4); \
    ako += 64; \
} while (0)

#define AWRITE(AW) do { \
    s16x8 w0, w1; \
    w0[0] = (short)f2b(av0.x); w0[1] = (short)f2b(av0.y); \
    w0[2] = (short)f2b(av0.z); w0[3] = (short)f2b(av0.w); \
    w0[4] = (short)f2b(av1.x); w0[5] = (short)f2b(av1.y); \
    w0[6] = (short)f2b(av1.z); w0[7] = (short)f2b(av1.w); \
    w1[0] = (short)f2b(av2.x); w1[1] = (short)f2b(av2.y); \
    w1[2] = (short)f2b(av2.z); w1[3] = (short)f2b(av2.w); \
    w1[4] = (short)f2b(av3.x); w1[5] = (short)f2b(av3.y); \
    w1[6] = (short)f2b(av3.z); w1[7] = (short)f2b(av3.w); \
    *(s16x8*)(wA0 + (AW) * 8192) = w0; \
    *(s16x8*)(wA1 + (AW) * 8192) = w1; \
} while (0)

#define BGLOAD(SB) do { \
    GLOAD16(sb, lds_b + (SB) * 8192 + t0 * 8); \
    GLOAD16(sb + (size_t)64 * KP1, lds_b + (SB) * 8192 + 4096 + t0 * 8); \
    sb += 64; \
} while (0)

    // ---------------- prologue: A0,A1 in LDS; A2 in regs; B0,B1 staged ----------
    AISSUE();                                           // tile 0
    asm volatile("s_waitcnt vmcnt(0)" ::: "memory");
    AWRITE(0);
    AISSUE();                                           // tile 1
    asm volatile("s_waitcnt vmcnt(0)" ::: "memory");
    AWRITE(1);
    BGLOAD(0);
    AISSUE();                                           // tile 2 -> regs (in flight)
    __builtin_amdgcn_sched_barrier(0);
    BGLOAD(1);
    // queue: B(0)[2], A(2)[4], B(1)[2]
    asm volatile("s_waitcnt vmcnt(6) lgkmcnt(0)" ::: "memory");  // B(0) + A-writes
    __builtin_amdgcn_s_barrier();
    __builtin_amdgcn_sched_barrier(0);
    // entry t=0: outstanding = A(2)[4] (oldest), B(1)[2]

// Step t: AR=t%3 (read A), AW=(t+2)%3 (write A), BB=t&1 (B buffer).
// entry vmcnt(2): A(t+2) regs landed (A issued before B each step -> oldest).
#define FSTEP(AR, AW, BB, DOAI, WN) do { \
    asm volatile("s_waitcnt vmcnt(2)" ::: "memory");  /* A(t+2) landed */ \
    __builtin_amdgcn_sched_barrier(0); \
    AWRITE(AW);                              /* tile t+2 -> lds_a[AW] (safe: last */ \
    if (DOAI) { AISSUE(); }                  /* readers were step t-1) */ \
    __builtin_amdgcn_sched_barrier(0); \
    s16x8 af[2][2], bv[2][4]; \
    _Pragma("unroll") \
    for (int kk = 0; kk < 2; ++kk) { \
        int ch = ((((kk << 2) | c0) ^ xr) << 3); \
        _Pragma("unroll") \
        for (int fm = 0; fm < 2; ++fm) \
            af[kk][fm] = *(const s16x8*)&lds_a[(AR) * 8192 + (ra0 + fm * 16) * 64 + ch]; \
        _Pragma("unroll") \
        for (int fn = 0; fn < 4; ++fn) \
            bv[kk][fn] = *(const s16x8*)&lds_b[(BB) * 8192 + (rb0 + fn * 16) * 64 + ch]; \
    } \
    asm volatile("s_waitcnt lgkmcnt(0)" ::: "memory"); \
    __builtin_amdgcn_sched_barrier(0); \
    __builtin_amdgcn_s_barrier();            /* all waves done reading B[BB] */ \
    __builtin_amdgcn_sched_barrier(0); \
    BGLOAD(BB);                              /* B tile t+2 over B[BB] */ \
    __builtin_amdgcn_s_setprio(1); \
    _Pragma("unroll") \
    for (int kk = 0; kk < 2; ++kk) \
        _Pragma("unroll") \
        for (int fm = 0; fm < 2; ++fm) \
            _Pragma("unroll") \
            for (int fn = 0; fn < 4; ++fn) \
                acc[fm][fn] = __builtin_amdgcn_mfma_f32_16x16x32_bf16( \
                    af[kk][fm], bv[kk][fn], acc[fm][fn], 0, 0, 0); \
    __builtin_amdgcn_s_setprio(0); \
    asm volatile("s_waitcnt vmcnt(" #WN ")" ::: "memory"); /* B(t+1) landed */ \
    __builtin_amdgcn_s_barrier(); \
    __builtin_amdgcn_sched_barrier(0); \
} while (0)

// Tail step: no staging. DRAIN=1 waits remaining loads + barrier (before last tile).
#define TSTEP(AR, BB, DRAIN) do { \
    s16x8 af[2][2], bv[2][4]; \
    _Pragma("unroll") \
    for (int kk = 0; kk < 2; ++kk) { \
        int ch = ((((kk << 2) | c0) ^ xr) << 3); \
        _Pragma("unroll") \
        for (int fm = 0; fm < 2; ++fm) \
            af[kk][fm] = *(const s16x8*)&lds_a[(AR) * 8192 + (ra0 + fm * 16) * 64 + ch]; \
        _Pragma("unroll") \
        for (int fn = 0; fn < 4; ++fn) \
            bv[kk][fn] = *(const s16x8*)&lds_b[(BB) * 8192 + (rb0 + fn * 16) * 64 + ch]; \
    } \
    asm volatile("s_waitcnt lgkmcnt(0)" ::: "memory"); \
    __builtin_amdgcn_sched_barrier(0); \
    _Pragma("unroll") \
    for (int kk = 0; kk < 2; ++kk) \
        _Pragma("unroll") \
        for (int fm = 0; fm < 2; ++fm) \
            _Pragma("unroll") \
            for (int fn = 0; fn < 4; ++fn) \
                acc[fm][fn] = __builtin_amdgcn_mfma_f32_16x16x32_bf16( \
                    af[kk][fm], bv[kk][fn], acc[fm][fn], 0, 0, 0); \
    if (DRAIN) { \
        asm volatile("s_waitcnt vmcnt(0)" ::: "memory"); \
        __builtin_amdgcn_s_barrier(); \
        __builtin_amdgcn_sched_barrier(0); \
    } \
} while (0)

    // 44 tiles: steps 0..41 staged (AISSUE through step 40 = tile 43), 2 tails.
    // (AR,AW,BB) cycle with period 6; 36 steps looped + 6 explicit.
    for (int it = 0; it < 6; ++it) {
        FSTEP(0, 2, 0, 1, 6);
        FSTEP(1, 0, 1, 1, 6);
        FSTEP(2, 1, 0, 1, 6);
        FSTEP(0, 2, 1, 1, 6);
        FSTEP(1, 0, 0, 1, 6);
        FSTEP(2, 1, 1, 1, 6);
    }
    FSTEP(0, 2, 0, 1, 6);   // t=36
    FSTEP(1, 0, 1, 1, 6);   // t=37
    FSTEP(2, 1, 0, 1, 6);   // t=38
    FSTEP(0, 2, 1, 1, 6);   // t=39
    FSTEP(1, 0, 0, 1, 6);   // t=40, AISSUE(43)
    FSTEP(2, 1, 1, 0, 2);   // t=41, AWRITE(43), no AISSUE; drain B(42)
    TSTEP(0, 0, 1);         // t=42, then drain B(43)
    TSTEP(1, 1, 0);         // t=43
#undef FSTEP
#undef TSTEP
#undef BGLOAD
#undef AWRITE
#undef AISSUE

    // epilogue: C/D map col=lane&15, row=(lane>>4)*4+j  [m89-verified]
    int rGrp = (lane >> 4) << 2;
    int cLane = lane & 15;
    #pragma unroll
    for (int fm = 0; fm < 2; ++fm) {
        int r0 = rowBase + wm * 32 + fm * 16 + rGrp;
        float pwv[4];
        #pragma unroll
        for (int j = 0; j < 4; ++j) pwv[j] = pw[(size_t)(r0 + j) * 4 + p];
        #pragma unroll
        for (int fn = 0; fn < 4; ++fn) {
            int c = colBase + wn * 64 + fn * 16 + cLane;
            f32x4 a = acc[fm][fn];
            #pragma unroll
            for (int j = 0; j < 4; ++j) {
                float x = a[j] * pwv[j];
                float s = x / (1.f + __expf(-x));
                C[(size_t)(r0 + j) * MCOLS + c] = f2b(s);
            }
        }
    }
}

// ---------------- Layers 2/3: 128x128 tile, 2x2 waves, BK=64 (block-diag) -------
// [R1/R5-proven tail]
template<int USE_PW>
__global__ __launch_bounds__(256, 2) void gemm_silu(
    const unsigned short* __restrict__ A, int lda,
    const unsigned short* __restrict__ Bt, int ldb,
    int K, int aOffPerP,
    const float* __restrict__ pw,
    unsigned short* __restrict__ C)
{
    __shared__ __align__(16) unsigned short lds_a[128 * 64];
    __shared__ __align__(16) unsigned short lds_b[128 * 64];

    int bid = blockIdx.x;
    int colTile = bid & 7;
    int rowTile = bid >> 3;
    int rowBase = rowTile * 128;
    int colBase = colTile * 128;
    int p = colBase >> 8;
    int aOff = p * aOffPerP;

    int t = threadIdx.x;
    int wave = t >> 6;
    int lane = t & 63;
    int wm = wave >> 1, wn = wave & 1;

    int trow = t >> 3;
    int kcol = (((t & 7) ^ (trow & 7)) << 3);
    const unsigned short* srcA = A + (size_t)(rowBase + trow) * lda + aOff + kcol;
    const unsigned short* srcB = Bt + (size_t)(colBase + trow) * ldb + kcol;

    f32x4 acc[4][4];
    f32x4 z4 = {0.f, 0.f, 0.f, 0.f};
    #pragma unroll
    for (int i = 0; i < 4; ++i)
        #pragma unroll
        for (int j = 0; j < 4; ++j) acc[i][j] = z4;

    int rb = wm * 64 + (lane & 15);
    int cb = wn * 64 + (lane & 15);
    int c0 = lane >> 4;
    int xr = lane & 7;

    int KT = K >> 6;
    for (int kt = 0; kt < KT; ++kt) {
        #pragma unroll
        for (int i = 0; i < 4; ++i) {
            GLOAD16(srcA + (size_t)i * 32 * lda, lds_a + i * 2048 + wave * 512);
            GLOAD16(srcB + (size_t)i * 32 * ldb, lds_b + i * 2048 + wave * 512);
        }
        srcA += 64; srcB += 64;
        __syncthreads();

        #pragma unroll
        for (int kk = 0; kk < 2; ++kk) {
            s16x8 af[4], bfr[4];
            int ch = (((kk << 2) | c0) ^ xr) << 3;
            #pragma unroll
            for (int fm = 0; fm < 4; ++fm)
                af[fm] = *(const s16x8*)&lds_a[(rb + fm * 16) * 64 + ch];
            #pragma unroll
            for (int fn = 0; fn < 4; ++fn)
                bfr[fn] = *(const s16x8*)&lds_b[(cb + fn * 16) * 64 + ch];
            #pragma unroll
            for (int fm = 0; fm < 4; ++fm)
                #pragma unroll
                for (int fn = 0; fn < 4; ++fn)
                    acc[fm][fn] = __builtin_amdgcn_mfma_f32_16x16x32_bf16(
                        af[fm], bfr[fn], acc[fm][fn], 0, 0, 0);
        }
        __syncthreads();
    }

    int rGrp = (lane >> 4) << 2;
    int cLane = lane & 15;
    #pragma unroll
    for (int fm = 0; fm < 4; ++fm) {
        int r0 = rowBase + wm * 64 + fm * 16 + rGrp;
        float pwv[4];
        if (USE_PW) {
            #pragma unroll
            for (int j = 0; j < 4; ++j) pwv[j] = pw[(size_t)(r0 + j) * 4 + p];
        }
        #pragma unroll
        for (int fn = 0; fn < 4; ++fn) {
            int c = colBase + wn * 64 + fn * 16 + cLane;
            f32x4 a = acc[fm][fn];
            #pragma unroll
            for (int j = 0; j < 4; ++j) {
                float x = a[j];
                if (USE_PW) x *= pwv[j];
                float s = x / (1.f + __expf(-x));
                C[(size_t)(r0 + j) * MCOLS + c] = f2b(s);
            }
        }
    }
}

// e[n] = sum_{p,h} h3[n, p*256+h] * W4flat[p*256+h] * 0.5; atomicAdd(out[sidx[n]], e/40)
__global__ void finalize(const unsigned short* __restrict__ h3,
                         const float* __restrict__ W4,
                         const int* __restrict__ sidx,
                         float* __restrict__ out) {
    int atom = blockIdx.x * 4 + (threadIdx.x >> 6);
    int lane = threadIdx.x & 63;
    if (atom >= N_ATOMS) return;
    const uint32_t* hu = (const uint32_t*)(h3 + (size_t)atom * MCOLS) + lane * 8;
    const float* w = W4 + lane * 16;
    float sum = 0.f;
    #pragma unroll
    for (int i = 0; i < 8; ++i) {
        uint32_t u = hu[i];
        sum += b2f((unsigned short)(u & 0xffff)) * w[2 * i];
        sum += b2f((unsigned short)(u >> 16)) * w[2 * i + 1];
    }
    #pragma unroll
    for (int off = 32; off > 0; off >>= 1) sum += __shfl_down(sum, off);
    if (lane == 0) atomicAdd(out + sidx[atom], sum * 0.0125f);  // (1/sqrt(4))/40
}

extern "C" void kernel_launch(void* const* d_in, const int* in_sizes, int n_in,
                              void* d_out, int out_size, void* d_ws, size_t ws_size,
                              hipStream_t stream) {
    const float* features = (const float*)d_in[0];
    const float* W_comb   = (const float*)d_in[1];
    const float* W1       = (const float*)d_in[2];
    const float* W2       = (const float*)d_in[3];
    const float* W3       = (const float*)d_in[4];
    const float* W4       = (const float*)d_in[5];
    const int*   species  = (const int*)d_in[6];
    const int*   sidx     = (const int*)d_in[7];
    float* out = (float*)d_out;

    char* ws = (char*)d_ws;
    size_t off = 0;
    auto carve = [&](size_t bytes) {
        char* r = ws + off;
        off += (bytes + 255) & ~(size_t)255;
        return r;
    };
    unsigned short* B1t  = (unsigned short*)carve((size_t)1024 * KP1 * 2 + 4096); // 5.8 MB + slack
    unsigned short* B2t  = (unsigned short*)carve((size_t)1024 * 256 * 2);
    unsigned short* B3t  = (unsigned short*)carve((size_t)1024 * 256 * 2);
    float*          pw   = (float*)carve((size_t)NPAD * 4 * 4);
    unsigned short* h1   = (unsigned short*)carve((size_t)NPAD * 1024 * 2);  // 41.4 MB
    unsigned short* h2   = (unsigned short*)carve((size_t)NPAD * 1024 * 2);  // 41.4 MB
    carve(4096);                                                             // slack

    pack_w<<<dim3(KP1 / 32, 4), 256, 0, stream>>>(W1, B1t, NFEAT, KP1);
    prep_small<<<144, 256, 0, stream>>>(W2, W3, B2t, B3t, W_comb, species, pw, out);

    // layer 1 (fused fp32->bf16 A-path, A triple-buffer): -> h1
    gemm1_fused<<<158 * 8, 512, 0, stream>>>(features, B1t, pw, h1);
    // layer 2: block-diagonal, A col offset p*256
    gemm_silu<0><<<158 * 8, 256, 0, stream>>>(h1, 1024, B2t, 256, 256, 256, nullptr, h2);
    // layer 3
    gemm_silu<0><<<158 * 8, 256, 0, stream>>>(h2, 1024, B3t, 256, 256, 256, nullptr, h1);
    // layer 4 + segment sum
    finalize<<<N_ATOMS / 4, 256, 0, stream>>>(h1, W4, sidx, out);
}

// Round 8
// 266.781 us; speedup vs baseline: 1.7846x; 1.1906x over previous
//
#include <hip/hip_runtime.h>
#include <hip/hip_bf16.h>
#include <stdint.h>

#define N_ATOMS 20000
#define NFEAT   2784
#define KP1     2816      // 44 * 64, K-pad for layer 1 (2784 real + 32 zero)
#define SS      500
#define NPAD    20224     // 158 * 128
#define MCOLS   1024      // P*H

typedef __attribute__((ext_vector_type(8))) short s16x8;
typedef __attribute__((ext_vector_type(4))) float f32x4;

static __device__ __forceinline__ unsigned short f2b(float f) {
    __hip_bfloat16 h = __float2bfloat16(f);
    return __builtin_bit_cast(unsigned short, h);
}
static __device__ __forceinline__ float b2f(unsigned short u) {
    unsigned int x = ((unsigned int)u) << 16;
    return __builtin_bit_cast(float, x);
}

#define GLOAD16(g, l) __builtin_amdgcn_global_load_lds( \
    (const __attribute__((address_space(1))) void*)(g), \
    (__attribute__((address_space(3))) void*)(l), 16, 0, 0)

// ---------------- Fused prep: conv_feat + pack_w(W1) + W2/W3/pw/zero ------------
// blocks [0, 20000): feat fp32->bf16 K-pad copy (BW-bound, dominates)
// blocks [20000, 20352): pack W1 -> B1t (352 = 88 f-tiles x 4 p)
// blocks [20352, 20496): pack W2 (32) | pack W3 (32) | make_pw (79) | zero (1)
// One launch replaces three; small work rides in parallel with the conv stream.
// LESSON (R2/R6/R7): fusing the fp32->bf16 conversion INTO gemm1's A-path failed
// 3 structural ways (latency-on-critical-path; regset spill 400MB; residual
// spill 80MB + allocator pinned by sched_barriers). Keep conversion as a
// separate BW-bound pass. Do not revisit.
__global__ void prep_all(const float* __restrict__ F, unsigned short* __restrict__ feat,
                         const float* __restrict__ W1, unsigned short* __restrict__ B1t,
                         const float* __restrict__ W2, const float* __restrict__ W3,
                         unsigned short* __restrict__ B2t, unsigned short* __restrict__ B3t,
                         const float* __restrict__ Wc, const int* __restrict__ spec,
                         float* __restrict__ pw, float* __restrict__ out) {
    __shared__ unsigned short tile[32][256];
    int b = blockIdx.x;
    int t = threadIdx.x;
    if (b < N_ATOMS) {
        // conv_feat: row b
        const float4* src = (const float4*)(F + (size_t)b * NFEAT);
        unsigned short* dst = feat + (size_t)b * KP1;
        for (int g = t; g < KP1 / 4; g += 256) {
            float4 v;
            if (g < NFEAT / 4) v = src[g];
            else { v.x = 0.f; v.y = 0.f; v.z = 0.f; v.w = 0.f; }
            ushort4 o;
            o.x = f2b(v.x); o.y = f2b(v.y); o.z = f2b(v.z); o.w = f2b(v.w);
            *(ushort4*)(dst + g * 4) = o;
        }
    } else if (b < N_ATOMS + 352) {
        // pack W1: Bt[p*256+h][k] = W1[p][k][h], zeros for k >= NFEAT
        int bb = b - N_ATOMS;
        int p = bb / 88;
        int f0 = (bb % 88) * 32;
        #pragma unroll 4
        for (int i = 0; i < 32; ++i) {
            int f = f0 + i;
            float v = (f < NFEAT) ? W1[((size_t)p * NFEAT + f) * 256 + t] : 0.f;
            tile[i][t] = f2b(v);
        }
        __syncthreads();
        unsigned short* drow = B1t + (size_t)(p * 256 + t) * KP1 + f0;
        #pragma unroll
        for (int i = 0; i < 32; i += 4) {
            ushort4 o;
            o.x = tile[i][t]; o.y = tile[i + 1][t]; o.z = tile[i + 2][t]; o.w = tile[i + 3][t];
            *(ushort4*)(drow + i) = o;
        }
    } else {
        int bb = b - N_ATOMS - 352;   // 0..143
        if (bb < 64) {
            const float* W = (bb < 32) ? W2 : W3;
            unsigned short* Bt = (bb < 32) ? B2t : B3t;
            int b2 = bb & 31;
            int p = b2 >> 3;
            int f0 = (b2 & 7) * 32;
            #pragma unroll 4
            for (int i = 0; i < 32; ++i) {
                int f = f0 + i;
                tile[i][t] = f2b(W[((size_t)p * 256 + f) * 256 + t]);
            }
            __syncthreads();
            unsigned short* drow = Bt + (size_t)(p * 256 + t) * 256 + f0;
            #pragma unroll
            for (int i = 0; i < 32; i += 4) {
                ushort4 o;
                o.x = tile[i][t]; o.y = tile[i + 1][t]; o.z = tile[i + 2][t]; o.w = tile[i + 3][t];
                *(ushort4*)(drow + i) = o;
            }
        } else if (bb < 143) {
            int n = (bb - 64) * 256 + t;
            if (n < N_ATOMS) {
                int s = spec[n];
                float4 v = *(const float4*)(Wc + s * 4);
                *(float4*)(pw + n * 4) = v;
            }
        } else {
            for (int i = t; i < SS; i += 256) out[i] = 0.f;
        }
    }
}

// ---------------- Layer-1: 128x128 tile, 8 waves (4M x 2N), BK=64 ----------------
// [R1/R5-proven: 147-151 us, MfmaUtil ~34, FETCH ~150MB, conflicts 0] BYTE-IDENTICAL
// to R5. Double-buffered LDS 64KB -> 2 blocks/CU; 2-deep prefetch; counted
// vmcnt(4); raw s_barrier; (row&7) XOR chunk swizzle (linear LDS dest,
// inverse-swizzled global source, swizzled read).
// LESSON (R4): BK<64 is structurally bad (half-line fetches, L2 thrash,
// degenerate swizzle -> 4-way conflicts). Do not revisit.
__global__ __launch_bounds__(512, 4) void gemm1_pipe(
    const unsigned short* __restrict__ A,
    const unsigned short* __restrict__ Bt,
    const float* __restrict__ pw,
    unsigned short* __restrict__ C)
{
    __shared__ __align__(16) unsigned short lds_a[2 * 8192];   // 32 KB
    __shared__ __align__(16) unsigned short lds_b[2 * 8192];   // 32 KB

    int bid = blockIdx.x;
    int swz = (bid & 7) * 158 + (bid >> 3);  // bijective XCD chunking (1264 = 8*158)
    int rowTile = swz >> 3;                  // 0..157
    int colTile = swz & 7;                   // 0..7
    int rowBase = rowTile * 128;
    int colBase = colTile * 128;
    int p = colTile >> 1;                    // pseudo-species of this 128-col slab

    int t0 = threadIdx.x;
    int wave = t0 >> 6;
    int lane = t0 & 63;
    int wm = wave >> 1;      // 0..3  (32-row slab)
    int wn = wave & 1;       // 0..1  (64-col slab)

    int rA = t0 >> 3;                         // 0..63
    int ckl = ((t0 & 7) ^ (rA & 7)) << 3;     // inverse-swizzled k elem offset
    const unsigned short* sa = A + (size_t)(rowBase + rA) * KP1 + ckl;
    const unsigned short* sb = Bt + (size_t)(colBase + rA) * KP1 + ckl;

    int ra0 = wm * 32 + (lane & 15);
    int rb0 = wn * 64 + (lane & 15);
    int xr = lane & 7;
    int c0 = lane >> 4;

    f32x4 acc[2][4];
    f32x4 z4 = {0.f, 0.f, 0.f, 0.f};
    #pragma unroll
    for (int i = 0; i < 2; ++i)
        #pragma unroll
        for (int j = 0; j < 4; ++j) acc[i][j] = z4;

#define STAGE1(SB) do { \
    GLOAD16(sa,                     lds_a + (SB) * 8192 + t0 * 8); \
    GLOAD16(sa + (size_t)64 * KP1,  lds_a + (SB) * 8192 + 4096 + t0 * 8); \
    GLOAD16(sb,                     lds_b + (SB) * 8192 + t0 * 8); \
    GLOAD16(sb + (size_t)64 * KP1,  lds_b + (SB) * 8192 + 4096 + t0 * 8); \
    sa += 64; sb += 64; \
} while (0)

    STAGE1(0);
    STAGE1(1);
    asm volatile("s_waitcnt vmcnt(4)" ::: "memory");   // tile 0 landed
    __builtin_amdgcn_s_barrier();
    __builtin_amdgcn_sched_barrier(0);

#define FSTEP(CB) do { \
    s16x8 af[2][2], bv[2][4]; \
    _Pragma("unroll") \
    for (int kk = 0; kk < 2; ++kk) { \
        int ch = ((((kk << 2) | c0) ^ xr) << 3); \
        _Pragma("unroll") \
        for (int fm = 0; fm < 2; ++fm) \
            af[kk][fm] = *(const s16x8*)&lds_a[(CB) * 8192 + (ra0 + fm * 16) * 64 + ch]; \
        _Pragma("unroll") \
        for (int fn = 0; fn < 4; ++fn) \
            bv[kk][fn] = *(const s16x8*)&lds_b[(CB) * 8192 + (rb0 + fn * 16) * 64 + ch]; \
    } \
    asm volatile("s_waitcnt lgkmcnt(0)" ::: "memory"); \
    __builtin_amdgcn_sched_barrier(0); \
    __builtin_amdgcn_s_barrier();            /* all waves done reading CB */ \
    __builtin_amdgcn_sched_barrier(0); \
    STAGE1(CB);                              /* tile t+2 over CB */ \
    __builtin_amdgcn_s_setprio(1); \
    _Pragma("unroll") \
    for (int kk = 0; kk < 2; ++kk) \
        _Pragma("unroll") \
        for (int fm = 0; fm < 2; ++fm) \
            _Pragma("unroll") \
            for (int fn = 0; fn < 4; ++fn) \
                acc[fm][fn] = __builtin_amdgcn_mfma_f32_16x16x32_bf16( \
                    af[kk][fm], bv[kk][fn], acc[fm][fn], 0, 0, 0); \
    __builtin_amdgcn_s_setprio(0); \
    asm volatile("s_waitcnt vmcnt(4)" ::: "memory");   /* tile t+1 landed */ \
    __builtin_amdgcn_s_barrier(); \
    __builtin_amdgcn_sched_barrier(0); \
} while (0)

#define TSTEP(CB, DRAIN) do { \
    s16x8 af[2][2], bv[2][4]; \
    _Pragma("unroll") \
    for (int kk = 0; kk < 2; ++kk) { \
        int ch = ((((kk << 2) | c0) ^ xr) << 3); \
        _Pragma("unroll") \
        for (int fm = 0; fm < 2; ++fm) \
            af[kk][fm] = *(const s16x8*)&lds_a[(CB) * 8192 + (ra0 + fm * 16) * 64 + ch]; \
        _Pragma("unroll") \
        for (int fn = 0; fn < 4; ++fn) \
            bv[kk][fn] = *(const s16x8*)&lds_b[(CB) * 8192 + (rb0 + fn * 16) * 64 + ch]; \
    } \
    _Pragma("unroll") \
    for (int kk = 0; kk < 2; ++kk) \
        _Pragma("unroll") \
        for (int fm = 0; fm < 2; ++fm) \
            _Pragma("unroll") \
            for (int fn = 0; fn < 4; ++fn) \
                acc[fm][fn] = __builtin_amdgcn_mfma_f32_16x16x32_bf16( \
                    af[kk][fm], bv[kk][fn], acc[fm][fn], 0, 0, 0); \
    if (DRAIN) { \
        asm volatile("s_waitcnt vmcnt(0)" ::: "memory"); \
        __builtin_amdgcn_s_barrier(); \
        __builtin_amdgcn_sched_barrier(0); \
    } \
} while (0)

    // 44 tiles: 42 full steps (stage tiles 2..43) = 21 pairs, then 2 tail steps
    for (int it = 0; it < 21; ++it) {
        FSTEP(0);
        FSTEP(1);
    }
    TSTEP(0, 1);     // t=42, then drain tile 43
    TSTEP(1, 0);     // t=43
#undef FSTEP
#undef TSTEP
#undef STAGE1

    // epilogue: C/D map col=lane&15, row=(lane>>4)*4+j  [m89-verified]
    int rGrp = (lane >> 4) << 2;
    int cLane = lane & 15;
    #pragma unroll
    for (int fm = 0; fm < 2; ++fm) {
        int r0 = rowBase + wm * 32 + fm * 16 + rGrp;
        float pwv[4];
        #pragma unroll
        for (int j = 0; j < 4; ++j) pwv[j] = pw[(size_t)(r0 + j) * 4 + p];
        #pragma unroll
        for (int fn = 0; fn < 4; ++fn) {
            int c = colBase + wn * 64 + fn * 16 + cLane;
            f32x4 a = acc[fm][fn];
            #pragma unroll
            for (int j = 0; j < 4; ++j) {
                float x = a[j] * pwv[j];
                float s = x / (1.f + __expf(-x));
                C[(size_t)(r0 + j) * MCOLS + c] = f2b(s);
            }
        }
    }
}

// ---------------- Layer 2: 128x128 tile, 2x2 waves, BK=64 (block-diag) ----------
// [R1/R5-proven]
template<int USE_PW>
__global__ __launch_bounds__(256, 2) void gemm_silu(
    const unsigned short* __restrict__ A, int lda,
    const unsigned short* __restrict__ Bt, int ldb,
    int K, int aOffPerP,
    const float* __restrict__ pw,
    unsigned short* __restrict__ C)
{
    __shared__ __align__(16) unsigned short lds_a[128 * 64];
    __shared__ __align__(16) unsigned short lds_b[128 * 64];

    int bid = blockIdx.x;
    int colTile = bid & 7;
    int rowTile = bid >> 3;
    int rowBase = rowTile * 128;
    int colBase = colTile * 128;
    int p = colBase >> 8;
    int aOff = p * aOffPerP;

    int t = threadIdx.x;
    int wave = t >> 6;
    int lane = t & 63;
    int wm = wave >> 1, wn = wave & 1;

    int trow = t >> 3;
    int kcol = (((t & 7) ^ (trow & 7)) << 3);
    const unsigned short* srcA = A + (size_t)(rowBase + trow) * lda + aOff + kcol;
    const unsigned short* srcB = Bt + (size_t)(colBase + trow) * ldb + kcol;

    f32x4 acc[4][4];
    f32x4 z4 = {0.f, 0.f, 0.f, 0.f};
    #pragma unroll
    for (int i = 0; i < 4; ++i)
        #pragma unroll
        for (int j = 0; j < 4; ++j) acc[i][j] = z4;

    int rb = wm * 64 + (lane & 15);
    int cb = wn * 64 + (lane & 15);
    int c0 = lane >> 4;
    int xr = lane & 7;

    int KT = K >> 6;
    for (int kt = 0; kt < KT; ++kt) {
        #pragma unroll
        for (int i = 0; i < 4; ++i) {
            GLOAD16(srcA + (size_t)i * 32 * lda, lds_a + i * 2048 + wave * 512);
            GLOAD16(srcB + (size_t)i * 32 * ldb, lds_b + i * 2048 + wave * 512);
        }
        srcA += 64; srcB += 64;
        __syncthreads();

        #pragma unroll
        for (int kk = 0; kk < 2; ++kk) {
            s16x8 af[4], bfr[4];
            int ch = (((kk << 2) | c0) ^ xr) << 3;
            #pragma unroll
            for (int fm = 0; fm < 4; ++fm)
                af[fm] = *(const s16x8*)&lds_a[(rb + fm * 16) * 64 + ch];
            #pragma unroll
            for (int fn = 0; fn < 4; ++fn)
                bfr[fn] = *(const s16x8*)&lds_b[(cb + fn * 16) * 64 + ch];
            #pragma unroll
            for (int fm = 0; fm < 4; ++fm)
                #pragma unroll
                for (int fn = 0; fn < 4; ++fn)
                    acc[fm][fn] = __builtin_amdgcn_mfma_f32_16x16x32_bf16(
                        af[fm], bfr[fn], acc[fm][fn], 0, 0, 0);
        }
        __syncthreads();
    }

    int rGrp = (lane >> 4) << 2;
    int cLane = lane & 15;
    #pragma unroll
    for (int fm = 0; fm < 4; ++fm) {
        int r0 = rowBase + wm * 64 + fm * 16 + rGrp;
        float pwv[4];
        if (USE_PW) {
            #pragma unroll
            for (int j = 0; j < 4; ++j) pwv[j] = pw[(size_t)(r0 + j) * 4 + p];
        }
        #pragma unroll
        for (int fn = 0; fn < 4; ++fn) {
            int c = colBase + wn * 64 + fn * 16 + cLane;
            f32x4 a = acc[fm][fn];
            #pragma unroll
            for (int j = 0; j < 4; ++j) {
                float x = a[j];
                if (USE_PW) x *= pwv[j];
                float s = x / (1.f + __expf(-x));
                C[(size_t)(r0 + j) * MCOLS + c] = f2b(s);
            }
        }
    }
}

// ---------------- Layer 3 + 4 fused: GEMM + silu + dot(W4) -> row partials ------
// Same GEMM body as gemm_silu (K=256, block-diag). Epilogue: instead of writing
// h3 (41MB) for finalize to re-read (41MB), compute the W4 dot in-register:
// per lane partial over its 4 cols, shfl_xor 1/2/4/8 reduces the 16-lane column
// group, cLane==0 writes ep[row][colTile*2+wn] (1.3MB, L2-merged). Avoids the
// 323k-atomic contention of a direct atomicAdd epilogue.
__global__ __launch_bounds__(256, 2) void gemm_dot3(
    const unsigned short* __restrict__ A,    // h2, lda 1024, block-diag p*256
    const unsigned short* __restrict__ Bt,   // B3t, ldb 256
    const float* __restrict__ W4,            // flat [1024]
    float* __restrict__ ep)                  // [NPAD][16] partials
{
    __shared__ __align__(16) unsigned short lds_a[128 * 64];
    __shared__ __align__(16) unsigned short lds_b[128 * 64];

    int bid = blockIdx.x;
    int colTile = bid & 7;
    int rowTile = bid >> 3;
    int rowBase = rowTile * 128;
    int colBase = colTile * 128;
    int p = colBase >> 8;
    int aOff = p * 256;

    int t = threadIdx.x;
    int wave = t >> 6;
    int lane = t & 63;
    int wm = wave >> 1, wn = wave & 1;

    int trow = t >> 3;
    int kcol = (((t & 7) ^ (trow & 7)) << 3);
    const unsigned short* srcA = A + (size_t)(rowBase + trow) * 1024 + aOff + kcol;
    const unsigned short* srcB = Bt + (size_t)(colBase + trow) * 256 + kcol;

    f32x4 acc[4][4];
    f32x4 z4 = {0.f, 0.f, 0.f, 0.f};
    #pragma unroll
    for (int i = 0; i < 4; ++i)
        #pragma unroll
        for (int j = 0; j < 4; ++j) acc[i][j] = z4;

    int rb = wm * 64 + (lane & 15);
    int cb = wn * 64 + (lane & 15);
    int c0 = lane >> 4;
    int xr = lane & 7;

    for (int kt = 0; kt < 4; ++kt) {
        #pragma unroll
        for (int i = 0; i < 4; ++i) {
            GLOAD16(srcA + (size_t)i * 32 * 1024, lds_a + i * 2048 + wave * 512);
            GLOAD16(srcB + (size_t)i * 32 * 256,  lds_b + i * 2048 + wave * 512);
        }
        srcA += 64; srcB += 64;
        __syncthreads();

        #pragma unroll
        for (int kk = 0; kk < 2; ++kk) {
            s16x8 af[4], bfr[4];
            int ch = (((kk << 2) | c0) ^ xr) << 3;
            #pragma unroll
            for (int fm = 0; fm < 4; ++fm)
                af[fm] = *(const s16x8*)&lds_a[(rb + fm * 16) * 64 + ch];
            #pragma unroll
            for (int fn = 0; fn < 4; ++fn)
                bfr[fn] = *(const s16x8*)&lds_b[(cb + fn * 16) * 64 + ch];
            #pragma unroll
            for (int fm = 0; fm < 4; ++fm)
                #pragma unroll
                for (int fn = 0; fn < 4; ++fn)
                    acc[fm][fn] = __builtin_amdgcn_mfma_f32_16x16x32_bf16(
                        af[fm], bfr[fn], acc[fm][fn], 0, 0, 0);
        }
        __syncthreads();
    }

    // epilogue: e_partial[row] = sum over this wave's 64 cols of silu(x)*W4[c]
    int rGrp = (lane >> 4) << 2;
    int cLane = lane & 15;
    float w4v[4];
    #pragma unroll
    for (int fn = 0; fn < 4; ++fn)
        w4v[fn] = W4[colBase + wn * 64 + fn * 16 + cLane];
    #pragma unroll
    for (int fm = 0; fm < 4; ++fm) {
        #pragma unroll
        for (int j = 0; j < 4; ++j) {
            float s = 0.f;
            #pragma unroll
            for (int fn = 0; fn < 4; ++fn) {
                float x = acc[fm][fn][j];
                s += (x / (1.f + __expf(-x))) * w4v[fn];
            }
            s += __shfl_xor(s, 1);
            s += __shfl_xor(s, 2);
            s += __shfl_xor(s, 4);
            s += __shfl_xor(s, 8);
            if (cLane == 0) {
                int row = rowBase + wm * 64 + fm * 16 + rGrp + j;
                ep[(size_t)row * 16 + colTile * 2 + wn] = s;
            }
        }
    }
}

// sum the 16 per-column-slab partials; one atomicAdd per atom (as before)
__global__ void finalize2(const float* __restrict__ ep, const int* __restrict__ sidx,
                          float* __restrict__ out) {
    int n = blockIdx.x * 256 + threadIdx.x;
    if (n >= N_ATOMS) return;
    const float4* v = (const float4*)(ep + (size_t)n * 16);
    float4 a = v[0], b = v[1], c = v[2], d = v[3];
    float s = (a.x + a.y + a.z + a.w) + (b.x + b.y + b.z + b.w)
            + (c.x + c.y + c.z + c.w) + (d.x + d.y + d.z + d.w);
    atomicAdd(out + sidx[n], s * 0.0125f);   // (1/sqrt(4))/40
}

extern "C" void kernel_launch(void* const* d_in, const int* in_sizes, int n_in,
                              void* d_out, int out_size, void* d_ws, size_t ws_size,
                              hipStream_t stream) {
    const float* features = (const float*)d_in[0];
    const float* W_comb   = (const float*)d_in[1];
    const float* W1       = (const float*)d_in[2];
    const float* W2       = (const float*)d_in[3];
    const float* W3       = (const float*)d_in[4];
    const float* W4       = (const float*)d_in[5];
    const int*   species  = (const int*)d_in[6];
    const int*   sidx     = (const int*)d_in[7];
    float* out = (float*)d_out;

    char* ws = (char*)d_ws;
    size_t off = 0;
    auto carve = [&](size_t bytes) {
        char* r = ws + off;
        off += (bytes + 255) & ~(size_t)255;
        return r;
    };
    unsigned short* feat = (unsigned short*)carve((size_t)NPAD * KP1 * 2);   // 113.9 MB
    unsigned short* B1t  = (unsigned short*)carve((size_t)1024 * KP1 * 2 + 4096); // 5.8 MB
    unsigned short* B2t  = (unsigned short*)carve((size_t)1024 * 256 * 2);
    unsigned short* B3t  = (unsigned short*)carve((size_t)1024 * 256 * 2);
    float*          pw   = (float*)carve((size_t)NPAD * 4 * 4);
    unsigned short* h1   = (unsigned short*)carve((size_t)NPAD * 1024 * 2);  // 41.4 MB
    float*          ep   = (float*)carve((size_t)NPAD * 16 * 4);             // 1.3 MB
    carve(4096);                                                             // slack
    unsigned short* h2   = feat;  // feat dead after gemm1; reuse as h2

    // all prep in one launch: conv_feat | pack W1 | pack W2/W3 | pw | zero-out
    prep_all<<<N_ATOMS + 352 + 144, 256, 0, stream>>>(
        features, feat, W1, B1t, W2, W3, B2t, B3t, W_comb, species, pw, out);

    // layer 1: [NPAD x 2816] * [2816 x 1024] -> h1 (pw-scaled silu), pipelined
    gemm1_pipe<<<158 * 8, 512, 0, stream>>>(feat, B1t, pw, h1);
    // layer 2: block-diagonal, A col offset p*256
    gemm_silu<0><<<158 * 8, 256, 0, stream>>>(h1, 1024, B2t, 256, 256, 256, nullptr, h2);
    // layer 3 + 4 fused: GEMM + silu + W4-dot -> per-row partials (no h3)
    gemm_dot3<<<158 * 8, 256, 0, stream>>>(h2, B3t, W4, ep);
    // sum partials + segment scatter
    finalize2<<<(N_ATOMS + 255) / 256, 256, 0, stream>>>(ep, sidx, out);
}